// Round 10
// baseline (636.074 us; speedup 1.0000x reference)
//
#include <hip/hip_runtime.h>
#include <hip/hip_bf16.h>

// GPR-GNN forward on MI355X.
// R10: (a) k_fill/k_count 4-edge ILP (R9 evidence: fill 44us at VALUBusy 0.7%
//      = single dependent chain); (b) k_prop processes a node PAIR per wave
//      with interleaved dual gather chains (32 edges in flight) + off-chain
//      self/hidden loads; (c) k_dinv folded into k_scan_c.

#define NFEAT 128
#define HID   256
#define NCLS  40
#define KHOPS 10

typedef __attribute__((ext_vector_type(8))) short short8;
typedef __attribute__((ext_vector_type(4))) float floatx4;

__device__ __forceinline__ float blo(unsigned g) { return __uint_as_float(g << 16); }
__device__ __forceinline__ float bhi(unsigned g) { return __uint_as_float(g & 0xffff0000u); }
__device__ __forceinline__ unsigned f2bf(float x) {          // RNE bf16 -> low 16
  unsigned u = __float_as_uint(x);
  return (u + 0x7fffu + ((u >> 16) & 1u)) >> 16;
}
__device__ __forceinline__ unsigned bpack(float a, float b) {
  return f2bf(a) | (f2bf(b) << 16);
}

// ---- storage probe: int64 values < 2^31 have all-zero odd 32-bit words ----
__global__ void k_detect64(const unsigned int* __restrict__ raw, int* __restrict__ flag) {
  __shared__ int any;
  int t = threadIdx.x;
  if (t == 0) any = 0;
  __syncthreads();
  if (raw[2 * t + 1] != 0u) any = 1;
  __syncthreads();
  if (t == 0) flag[0] = (any == 0) ? 1 : 0;   // 1 => int64 storage
}

__global__ void k_zero(int* __restrict__ p, int n) {
  int i = blockIdx.x * blockDim.x + threadIdx.x;
  if (i < n) p[i] = 0;
}

// 4 edges per thread: coalesced int4 dst reads, 4 independent atomic chains.
__global__ void k_count(const int* __restrict__ ei32, const long long* __restrict__ ei64,
                        int E, int N, int* __restrict__ cnt, const int* __restrict__ flag) {
  int i = (blockIdx.x * blockDim.x + threadIdx.x) * 4;
  if (i >= E) return;
  int d[4];
  if (flag[0]) {
    #pragma unroll
    for (int j = 0; j < 4; ++j) d[j] = (i + j < E) ? (int)ei64[(size_t)E + i + j] : -1;
  } else if (i + 3 < E) {
    int4 v = *(const int4*)(ei32 + (size_t)E + i);
    d[0] = v.x; d[1] = v.y; d[2] = v.z; d[3] = v.w;
  } else {
    #pragma unroll
    for (int j = 0; j < 4; ++j) d[j] = (i + j < E) ? ei32[(size_t)E + i + j] : -1;
  }
  #pragma unroll
  for (int j = 0; j < 4; ++j)
    if ((unsigned)d[j] < (unsigned)N) atomicAdd(&cnt[d[j]], 1);
}

// ---- 3-level parallel exclusive scan (tiles of 1024) ----
__global__ __launch_bounds__(256) void k_scan_a(
    const int* __restrict__ cnt, int* __restrict__ bsum, int n) {
  int t = threadIdx.x;
  int base = blockIdx.x * 1024 + t * 4;
  int s = 0;
  if (base + 3 < n) {
    int4 v = *(const int4*)(cnt + base);
    s = v.x + v.y + v.z + v.w;
  } else {
    #pragma unroll
    for (int j = 0; j < 4; ++j) if (base + j < n) s += cnt[base + j];
  }
  #pragma unroll
  for (int off = 1; off < 64; off <<= 1) s += __shfl_xor(s, off);
  __shared__ int ws[4];
  if ((t & 63) == 0) ws[t >> 6] = s;
  __syncthreads();
  if (t == 0) bsum[blockIdx.x] = ws[0] + ws[1] + ws[2] + ws[3];
}

__global__ void k_scan_mid(int* __restrict__ bsum, int* __restrict__ S,
                           int ntiles, int n) {
  int t = threadIdx.x;
  int lane = t & 63, wid = t >> 6;
  int v = (t < ntiles) ? bsum[t] : 0;
  int x = v;
  #pragma unroll
  for (int off = 1; off < 64; off <<= 1) {
    int u = __shfl_up(x, off);
    if (lane >= off) x += u;
  }
  __shared__ int ws[16];
  if (lane == 63) ws[wid] = x;
  __syncthreads();
  if (wid == 0) {
    int s2 = (lane < 16) ? ws[lane] : 0;
    #pragma unroll
    for (int off = 1; off < 16; off <<= 1) {
      int u = __shfl_up(s2, off);
      if (lane >= off) s2 += u;
    }
    if (lane < 16) ws[lane] = s2;
  }
  __syncthreads();
  int woff = wid ? ws[wid - 1] : 0;
  if (t < ntiles) bsum[t] = x - v + woff;   // exclusive tile offsets
  if (t == 0) S[n] = ws[15];                // grand total sentinel
}

// per-tile scan + apply; also emits dinv (counts are in registers here)
__global__ __launch_bounds__(256) void k_scan_c(
    const int* __restrict__ cnt, const int* __restrict__ bsum,
    int* __restrict__ S, int* __restrict__ cursor, float* __restrict__ dinv, int n) {
  int t = threadIdx.x;
  int base = blockIdx.x * 1024 + t * 4;
  int v[4];
  if (base + 3 < n) {
    int4 q = *(const int4*)(cnt + base);
    v[0] = q.x; v[1] = q.y; v[2] = q.z; v[3] = q.w;
  } else {
    #pragma unroll
    for (int j = 0; j < 4; ++j) v[j] = (base + j < n) ? cnt[base + j] : 0;
  }
  int tsum = v[0] + v[1] + v[2] + v[3];
  int lane = t & 63, wv = t >> 6;
  int x = tsum;
  #pragma unroll
  for (int off = 1; off < 64; off <<= 1) {
    int u = __shfl_up(x, off);
    if (lane >= off) x += u;
  }
  __shared__ int ws[4];
  if (lane == 63) ws[wv] = x;
  __syncthreads();
  int woff = 0;
  #pragma unroll
  for (int j = 0; j < 4; ++j) if (j < wv) woff += ws[j];
  int run = x - tsum + woff + bsum[blockIdx.x];
  #pragma unroll
  for (int j = 0; j < 4; ++j) {
    int idx = base + j;
    if (idx < n) {
      S[idx] = run;
      cursor[idx] = run;
      dinv[idx] = rsqrtf((float)(v[j] + 1));
      run += v[j];
    }
  }
}

// 4 edges per thread: coalesced int4 src+dst reads, 4 independent chains.
__global__ void k_fill(const int* __restrict__ ei32, const long long* __restrict__ ei64,
                       int E, int N, const float* __restrict__ dinv,
                       int* __restrict__ cursor, int2* __restrict__ csr,
                       const int* __restrict__ flag) {
  int i = (blockIdx.x * blockDim.x + threadIdx.x) * 4;
  if (i >= E) return;
  int sr[4], ds[4];
  if (flag[0]) {
    #pragma unroll
    for (int j = 0; j < 4; ++j) {
      sr[j] = (i + j < E) ? (int)ei64[i + j] : -1;
      ds[j] = (i + j < E) ? (int)ei64[(size_t)E + i + j] : -1;
    }
  } else if (i + 3 < E) {
    int4 a = *(const int4*)(ei32 + i);
    int4 b = *(const int4*)(ei32 + (size_t)E + i);
    sr[0] = a.x; sr[1] = a.y; sr[2] = a.z; sr[3] = a.w;
    ds[0] = b.x; ds[1] = b.y; ds[2] = b.z; ds[3] = b.w;
  } else {
    #pragma unroll
    for (int j = 0; j < 4; ++j) {
      sr[j] = (i + j < E) ? ei32[i + j] : -1;
      ds[j] = (i + j < E) ? ei32[(size_t)E + i + j] : -1;
    }
  }
  #pragma unroll
  for (int j = 0; j < 4; ++j) {
    if ((unsigned)sr[j] >= (unsigned)N || (unsigned)ds[j] >= (unsigned)N) continue;
    int p = atomicAdd(&cursor[ds[j]], 1);
    float w = dinv[sr[j]] * dinv[ds[j]];
    csr[p] = make_int2(sr[j], __float_as_int(w));
  }
}

// fused init: x -> h2 (bf16x2) and hidden32 = temp[0]*x  (single x read)
__global__ void k_init(const float* __restrict__ x, const float* __restrict__ temp,
                       unsigned* __restrict__ h2, float* __restrict__ hidden,
                       int total64) {
  int i = blockIdx.x * blockDim.x + threadIdx.x;
  if (i >= total64) return;
  float2 xv = ((const float2*)x)[i];
  h2[i] = bpack(xv.x, xv.y);
  float t0 = temp[0];
  ((float2*)hidden)[i] = make_float2(t0 * xv.x, t0 * xv.y);
}

// One wave per NODE PAIR. lane = e*16+g (g: features 8g..8g+7, e: edge
// subgroup). Both nodes' 16-deep gather batches interleave in one loop:
// 32 edges in flight, two independent chains. Self-row + hidden loads issue
// after the loop, covered by the shfl reduce. Epilogues on e==0 / e==1.
// mode 0: write h_new bf16 + RMW f32 hidden; mode 1: write final bf16 hidden.
__global__ __launch_bounds__(256) void k_prop(
    const unsigned* __restrict__ h2, unsigned* __restrict__ hnew2,
    float* __restrict__ hidden,
    const int* __restrict__ S, const int2* __restrict__ csr,
    const float* __restrict__ dinv, const float* __restrict__ temp,
    int k, int N, int mode) {
  int wid = __builtin_amdgcn_readfirstlane(threadIdx.x >> 6);
  int lane = threadIdx.x & 63;
  int n0 = (blockIdx.x * 4 + wid) * 2;       // uniform (SGPR) per wave
  if (n0 >= N) return;
  int nB = n0 + 1;
  bool two = nB < N;
  int g = lane & 15;
  int e = lane >> 4;
  int sA = S[n0];
  int enA = S[n0 + 1];
  int sB = enA;
  int enB = two ? S[n0 + 2] : enA;
  float diA = dinv[n0];
  float diB = two ? dinv[nB] : 0.f;

  float accA[8] = {0.f, 0.f, 0.f, 0.f, 0.f, 0.f, 0.f, 0.f};
  float accB[8] = {0.f, 0.f, 0.f, 0.f, 0.f, 0.f, 0.f, 0.f};
  int degA = enA - sA, degB = enB - sB;
  int nb = degA > degB ? degA : degB;
  for (int off = 0; off < nb; off += 16) {
    uint4 gdA[4], gdB[4];
    float wtA[4], wtB[4];
    #pragma unroll
    for (int t = 0; t < 4; ++t) {
      int pjA = sA + off + t * 4 + e;
      int2 edA = csr[pjA < enA ? pjA : sA];          // clamp: valid (loop ran)
      wtA[t] = (pjA < enA) ? __int_as_float(edA.y) : 0.f;
      gdA[t] = *(const uint4*)(h2 + (size_t)edA.x * 64 + g * 4);
      int pjB = sB + off + t * 4 + e;
      int2 edB = csr[(two && pjB < enB) ? pjB : sA]; // clamp to sA: valid
      wtB[t] = (two && pjB < enB) ? __int_as_float(edB.y) : 0.f;
      gdB[t] = *(const uint4*)(h2 + (size_t)edB.x * 64 + g * 4);
    }
    #pragma unroll
    for (int t = 0; t < 4; ++t) {
      const unsigned* ga = (const unsigned*)&gdA[t];
      const unsigned* gb = (const unsigned*)&gdB[t];
      #pragma unroll
      for (int u = 0; u < 4; ++u) {
        accA[u * 2]     += wtA[t] * blo(ga[u]);
        accA[u * 2 + 1] += wtA[t] * bhi(ga[u]);
        accB[u * 2]     += wtB[t] * blo(gb[u]);
        accB[u * 2 + 1] += wtB[t] * bhi(gb[u]);
      }
    }
  }
  // off-chain loads: issued here, latency covered by the 32-op shfl reduce
  uint4 gsA = *(const uint4*)(h2 + (size_t)n0 * 64 + g * 4);
  uint4 gsB = two ? *(const uint4*)(h2 + (size_t)nB * 64 + g * 4)
                  : make_uint4(0u, 0u, 0u, 0u);
  float4 hX0, hX1;                            // e==0 -> node A row, e==1 -> node B
  float4* hpA = (float4*)(hidden + (size_t)n0 * NFEAT + g * 8);
  float4* hpB = (float4*)(hidden + (size_t)nB * NFEAT + g * 8);
  if (e == 0)            { hX0 = hpA[0]; hX1 = hpA[1]; }
  else if (e == 1 && two){ hX0 = hpB[0]; hX1 = hpB[1]; }
  #pragma unroll
  for (int u = 0; u < 8; ++u) {
    accA[u] += __shfl_xor(accA[u], 16);
    accA[u] += __shfl_xor(accA[u], 32);
    accB[u] += __shfl_xor(accB[u], 16);
    accB[u] += __shfl_xor(accB[u], 32);
  }
  float tk = temp[k + 1];
  if (e == 0) {
    float dd = diA * diA;
    const unsigned* su = (const unsigned*)&gsA;
    #pragma unroll
    for (int u = 0; u < 4; ++u) {
      accA[u * 2]     += dd * blo(su[u]);
      accA[u * 2 + 1] += dd * bhi(su[u]);
    }
    hX0.x += tk * accA[0];  hX0.y += tk * accA[1];
    hX0.z += tk * accA[2];  hX0.w += tk * accA[3];
    hX1.x += tk * accA[4];  hX1.y += tk * accA[5];
    hX1.z += tk * accA[6];  hX1.w += tk * accA[7];
    uint4 pk;
    if (mode == 0) {
      pk.x = bpack(accA[0], accA[1]);  pk.y = bpack(accA[2], accA[3]);
      pk.z = bpack(accA[4], accA[5]);  pk.w = bpack(accA[6], accA[7]);
      *(uint4*)(hnew2 + (size_t)n0 * 64 + g * 4) = pk;
      hpA[0] = hX0;  hpA[1] = hX1;
    } else {
      pk.x = bpack(hX0.x, hX0.y);  pk.y = bpack(hX0.z, hX0.w);
      pk.z = bpack(hX1.x, hX1.y);  pk.w = bpack(hX1.z, hX1.w);
      *(uint4*)(hnew2 + (size_t)n0 * 64 + g * 4) = pk;
    }
  } else if (e == 1 && two) {
    float dd = diB * diB;
    const unsigned* su = (const unsigned*)&gsB;
    #pragma unroll
    for (int u = 0; u < 4; ++u) {
      accB[u * 2]     += dd * blo(su[u]);
      accB[u * 2 + 1] += dd * bhi(su[u]);
    }
    hX0.x += tk * accB[0];  hX0.y += tk * accB[1];
    hX0.z += tk * accB[2];  hX0.w += tk * accB[3];
    hX1.x += tk * accB[4];  hX1.y += tk * accB[5];
    hX1.z += tk * accB[6];  hX1.w += tk * accB[7];
    uint4 pk;
    if (mode == 0) {
      pk.x = bpack(accB[0], accB[1]);  pk.y = bpack(accB[2], accB[3]);
      pk.z = bpack(accB[4], accB[5]);  pk.w = bpack(accB[6], accB[7]);
      *(uint4*)(hnew2 + (size_t)nB * 64 + g * 4) = pk;
      hpB[0] = hX0;  hpB[1] = hX1;
    } else {
      pk.x = bpack(hX0.x, hX0.y);  pk.y = bpack(hX0.z, hX0.w);
      pk.z = bpack(hX1.x, hX1.y);  pk.w = bpack(hX1.z, hX1.w);
      *(uint4*)(hnew2 + (size_t)nB * 64 + g * 4) = pk;
    }
  }
}

// hidden_bf16 (Mx128) @ W1 (128x256 f32) + b1, relu -> z1 (Mx256 bf16).
__global__ __launch_bounds__(256) void k_gemm1(
    const unsigned short* __restrict__ Ab, const float* __restrict__ W1,
    const float* __restrict__ b1, unsigned short* __restrict__ z1, int M) {
  __shared__ unsigned short As[64][136];    // m-major, k contig, +8 pad
  __shared__ unsigned short Bs[16][128][8]; // [k>>3][n][k&7]: frag = ds_read_b128
  int tid = threadIdx.x;
  int m0 = blockIdx.x * 64;
  int n0 = blockIdx.y * 128;
  for (int idx = tid; idx < 64 * 16; idx += 256) {
    int m = idx >> 4, c = idx & 15;
    int row = m0 + m; if (row >= M) row = M - 1;
    uint4 v = *(const uint4*)(Ab + (size_t)row * NFEAT + c * 8);
    *(uint4*)&As[m][c * 8] = v;
  }
  for (int idx = tid; idx < 128 * 128; idx += 256) {
    int k = idx >> 7, n = idx & 127;
    Bs[k >> 3][n][k & 7] = (unsigned short)f2bf(W1[(size_t)k * HID + n0 + n]);
  }
  __syncthreads();
  int lane = tid & 63;
  int q = lane >> 4, r16 = lane & 15;
  int nw = (tid >> 6) * 32;
  floatx4 acc[4][2] = {};
  #pragma unroll
  for (int step = 0; step < 4; ++step) {
    int k0 = step * 32;
    short8 a[4], b[2];
    #pragma unroll
    for (int i = 0; i < 4; ++i)
      a[i] = *(const short8*)&As[i * 16 + r16][k0 + q * 8];
    #pragma unroll
    for (int j = 0; j < 2; ++j)
      b[j] = *(const short8*)&Bs[step * 4 + q][nw + j * 16 + r16][0];
    #pragma unroll
    for (int i = 0; i < 4; ++i)
      #pragma unroll
      for (int j = 0; j < 2; ++j)
        acc[i][j] = __builtin_amdgcn_mfma_f32_16x16x32_bf16(a[i], b[j], acc[i][j], 0, 0, 0);
  }
  __syncthreads();
  unsigned short* Zs = &As[0][0];
  #pragma unroll
  for (int j = 0; j < 2; ++j) {
    int n = nw + j * 16 + r16;
    float bias = b1[n0 + n];
    #pragma unroll
    for (int i = 0; i < 4; ++i) {
      #pragma unroll
      for (int r = 0; r < 4; ++r) {
        int m = i * 16 + q * 4 + r;
        float v = fmaxf(acc[i][j][r] + bias, 0.f);
        Zs[m * 136 + n] = (unsigned short)f2bf(v);
      }
    }
  }
  __syncthreads();
  for (int idx = tid; idx < 64 * 16; idx += 256) {
    int m = idx >> 4, c = idx & 15;
    int row = m0 + m;
    if (row < M) {
      uint4 v = *(const uint4*)&Zs[m * 136 + c * 8];
      *(uint4*)(z1 + (size_t)row * HID + n0 + c * 8) = v;
    }
  }
}

// W2 (256x40 f32) -> W2t bf16 [48][256] (n-major, k-contig; n>=40 zero-padded)
__global__ void k_w2prep(const float* __restrict__ W2, unsigned short* __restrict__ W2t) {
  int i = blockIdx.x * blockDim.x + threadIdx.x;
  if (i >= 48 * 256) return;
  int n = i >> 8, k = i & 255;
  W2t[n * 256 + k] = (n < NCLS) ? (unsigned short)f2bf(W2[(size_t)k * NCLS + n]) : 0;
}

// z1 (Mx256 bf16) @ W2t + b2 -> log_softmax -> out f32. LDS-free MFMA.
__global__ __launch_bounds__(256) void k_mlp2(
    const unsigned short* __restrict__ z1, const unsigned short* __restrict__ W2t,
    const float* __restrict__ b2, float* __restrict__ out, int N) {
  int tid = threadIdx.x;
  int lane = tid & 63;
  int wv = tid >> 6;
  int node0 = blockIdx.x * 64 + wv * 16;
  int q = lane >> 4, m = lane & 15;
  int arow = node0 + m; if (arow >= N) arow = N - 1;
  const unsigned short* aptr = z1 + (size_t)arow * HID + q * 8;
  const unsigned short* bptr = W2t + (size_t)m * HID + q * 8;   // + j*16*HID
  floatx4 acc[3] = {};
  #pragma unroll
  for (int step = 0; step < 8; ++step) {     // K = 8 x 32
    short8 a = *(const short8*)(aptr + step * 32);
    #pragma unroll
    for (int j = 0; j < 3; ++j) {
      short8 b = *(const short8*)(bptr + (size_t)j * 16 * HID + step * 32);
      acc[j] = __builtin_amdgcn_mfma_f32_16x16x32_bf16(a, b, acc[j], 0, 0, 0);
    }
  }
  int c = m;                                  // class within tile = col = lane&15
  bool v2 = (c < NCLS - 32);                  // c+32 < 40
  float bb0 = b2[c], bb1 = b2[c + 16];
  float bb2 = v2 ? b2[c + 32] : 0.f;
  #pragma unroll
  for (int r = 0; r < 4; ++r) {
    int node = node0 + q * 4 + r;
    float l0 = acc[0][r] + bb0;
    float l1 = acc[1][r] + bb1;
    float l2 = v2 ? (acc[2][r] + bb2) : -3.4e38f;
    float mx = fmaxf(fmaxf(l0, l1), l2);
    #pragma unroll
    for (int off = 1; off < 16; off <<= 1) mx = fmaxf(mx, __shfl_xor(mx, off));
    float sm = __expf(l0 - mx) + __expf(l1 - mx) + (v2 ? __expf(l2 - mx) : 0.f);
    #pragma unroll
    for (int off = 1; off < 16; off <<= 1) sm += __shfl_xor(sm, off);
    float lse = mx + __logf(sm);
    if (node < N) {
      float* op = out + (size_t)node * NCLS + c;
      op[0] = l0 - lse;
      op[16] = l1 - lse;
      if (v2) op[32] = l2 - lse;
    }
  }
}

extern "C" void kernel_launch(void* const* d_in, const int* in_sizes, int n_in,
                              void* d_out, int out_size, void* d_ws, size_t ws_size,
                              hipStream_t stream) {
  const float*     x    = (const float*)d_in[0];
  const int*       ei32 = (const int*)d_in[1];
  const long long* ei64 = (const long long*)d_in[1];
  const float*     temp = (const float*)d_in[2];
  const float*     W1   = (const float*)d_in[3];
  const float*     b1   = (const float*)d_in[4];
  const float*     W2   = (const float*)d_in[5];
  const float*     b2   = (const float*)d_in[6];
  float* out = (float*)d_out;

  int N = in_sizes[0] / NFEAT;   // 50000
  int E = in_sizes[1] / 2;       // 800000

  // workspace carve (~71 MB)
  char* w = (char*)d_ws;
  auto carve = [&](size_t bytes) -> void* {
    void* p = (void*)w;
    w += (bytes + 255) & ~(size_t)255;
    return p;
  };
  int*      flag      = (int*)     carve(4);
  int*      cnt       = (int*)     carve((size_t)N * 4);
  int*      S         = (int*)     carve(((size_t)N + 1) * 4);
  int*      cursor    = (int*)     carve((size_t)N * 4);
  float*    dinv      = (float*)   carve((size_t)N * 4);
  int*      bsum      = (int*)     carve(1024 * 4);
  unsigned short* W2t = (unsigned short*)carve(48 * 256 * 2);
  int2*     csr       = (int2*)    carve((size_t)E * 8);
  unsigned* h_a       = (unsigned*)carve((size_t)N * 64 * 4);   // bf16x2 rows
  unsigned* h_b       = (unsigned*)carve((size_t)N * 64 * 4);
  unsigned* hid       = (unsigned*)carve((size_t)N * 64 * 4);   // final hidden bf16
  float*    hidden32  = (float*)   carve((size_t)N * NFEAT * 4);
  unsigned short* z1  = (unsigned short*)hidden32;  // dead before gemm1 writes z1

  int ntiles = (N + 1023) / 1024;   // 49

  k_detect64<<<1, 256, 0, stream>>>((const unsigned int*)d_in[1], flag);
  k_zero<<<(N + 255) / 256, 256, 0, stream>>>(cnt, N);
  k_count<<<(E / 4 + 255) / 256, 256, 0, stream>>>(ei32, ei64, E, N, cnt, flag);
  k_scan_a<<<ntiles, 256, 0, stream>>>(cnt, bsum, N);
  k_scan_mid<<<1, 1024, 0, stream>>>(bsum, S, ntiles, N);
  k_scan_c<<<ntiles, 256, 0, stream>>>(cnt, bsum, S, cursor, dinv, N);
  k_fill<<<(E / 4 + 255) / 256, 256, 0, stream>>>(ei32, ei64, E, N, dinv,
                                                  cursor, csr, flag);
  k_init<<<(N * 64 + 255) / 256, 256, 0, stream>>>(x, temp, h_a, hidden32, N * 64);
  k_w2prep<<<48, 256, 0, stream>>>(W2, W2t);

  unsigned* hc = h_a;
  unsigned* hn = h_b;
  int pgrid = (N + 7) / 8;   // 4 waves/block x 2 nodes/wave
  for (int k = 0; k < KHOPS - 1; ++k) {
    k_prop<<<pgrid, 256, 0, stream>>>(
        hc, hn, hidden32, S, csr, dinv, temp, k, N, 0);
    unsigned* t2 = hc; hc = hn; hn = t2;
  }
  k_prop<<<pgrid, 256, 0, stream>>>(
      hc, hid, hidden32, S, csr, dinv, temp, KHOPS - 1, N, 1);

  k_gemm1<<<dim3((N + 63) / 64, 2), 256, 0, stream>>>(
      (const unsigned short*)hid, W1, b1, z1, N);
  k_mlp2<<<(N + 63) / 64, 256, 0, stream>>>(z1, W2t, b2, out, N);
}

// Round 11
// 537.144 us; speedup vs baseline: 1.1842x; 1.1842x over previous
//
#include <hip/hip_runtime.h>
#include <hip/hip_bf16.h>

// GPR-GNN forward on MI355X.
// R11: (a) weight elimination: ping-pong buffers store p = dinv*h, so
//      msg weight dinv[src]*dinv[dst] telescopes away -> CSR is 4B src only.
//      (b) rank trick: k_count stores atomicAdd's return; k_fill is atomic-free.
//      (c) k_count/k_fill back to 1 edge/thread (R10: batching cut occupancy).
//      (d) prop reverted to R9 single-node form (R10 pair-wave was neutral).

#define NFEAT 128
#define HID   256
#define NCLS  40
#define KHOPS 10

typedef __attribute__((ext_vector_type(8))) short short8;
typedef __attribute__((ext_vector_type(4))) float floatx4;

__device__ __forceinline__ float blo(unsigned g) { return __uint_as_float(g << 16); }
__device__ __forceinline__ float bhi(unsigned g) { return __uint_as_float(g & 0xffff0000u); }
__device__ __forceinline__ unsigned f2bf(float x) {          // RNE bf16 -> low 16
  unsigned u = __float_as_uint(x);
  return (u + 0x7fffu + ((u >> 16) & 1u)) >> 16;
}
__device__ __forceinline__ unsigned bpack(float a, float b) {
  return f2bf(a) | (f2bf(b) << 16);
}

// ---- storage probe: int64 values < 2^31 have all-zero odd 32-bit words ----
__global__ void k_detect64(const unsigned int* __restrict__ raw, int* __restrict__ flag) {
  __shared__ int any;
  int t = threadIdx.x;
  if (t == 0) any = 0;
  __syncthreads();
  if (raw[2 * t + 1] != 0u) any = 1;
  __syncthreads();
  if (t == 0) flag[0] = (any == 0) ? 1 : 0;   // 1 => int64 storage
}

__global__ void k_zero(int* __restrict__ p, int n) {
  int i = blockIdx.x * blockDim.x + threadIdx.x;
  if (i < n) p[i] = 0;
}

// 1 edge/thread; stores the atomic's return as this edge's rank within dst.
__global__ void k_count(const int* __restrict__ ei32, const long long* __restrict__ ei64,
                        int E, int N, int* __restrict__ cnt, int* __restrict__ rank,
                        const int* __restrict__ flag) {
  int e = blockIdx.x * blockDim.x + threadIdx.x;
  if (e >= E) return;
  int dst = flag[0] ? (int)ei64[(size_t)E + e] : ei32[(size_t)E + e];
  if ((unsigned)dst < (unsigned)N) rank[e] = atomicAdd(&cnt[dst], 1);
  else rank[e] = -1;
}

// ---- 3-level parallel exclusive scan (tiles of 1024) ----
__global__ __launch_bounds__(256) void k_scan_a(
    const int* __restrict__ cnt, int* __restrict__ bsum, int n) {
  int t = threadIdx.x;
  int base = blockIdx.x * 1024 + t * 4;
  int s = 0;
  if (base + 3 < n) {
    int4 v = *(const int4*)(cnt + base);
    s = v.x + v.y + v.z + v.w;
  } else {
    #pragma unroll
    for (int j = 0; j < 4; ++j) if (base + j < n) s += cnt[base + j];
  }
  #pragma unroll
  for (int off = 1; off < 64; off <<= 1) s += __shfl_xor(s, off);
  __shared__ int ws[4];
  if ((t & 63) == 0) ws[t >> 6] = s;
  __syncthreads();
  if (t == 0) bsum[blockIdx.x] = ws[0] + ws[1] + ws[2] + ws[3];
}

__global__ void k_scan_mid(int* __restrict__ bsum, int* __restrict__ S,
                           int ntiles, int n) {
  int t = threadIdx.x;
  int lane = t & 63, wid = t >> 6;
  int v = (t < ntiles) ? bsum[t] : 0;
  int x = v;
  #pragma unroll
  for (int off = 1; off < 64; off <<= 1) {
    int u = __shfl_up(x, off);
    if (lane >= off) x += u;
  }
  __shared__ int ws[16];
  if (lane == 63) ws[wid] = x;
  __syncthreads();
  if (wid == 0) {
    int s2 = (lane < 16) ? ws[lane] : 0;
    #pragma unroll
    for (int off = 1; off < 16; off <<= 1) {
      int u = __shfl_up(s2, off);
      if (lane >= off) s2 += u;
    }
    if (lane < 16) ws[lane] = s2;
  }
  __syncthreads();
  int woff = wid ? ws[wid - 1] : 0;
  if (t < ntiles) bsum[t] = x - v + woff;   // exclusive tile offsets
  if (t == 0) S[n] = ws[15];                // grand total sentinel
}

// per-tile scan + apply; also emits dinv (counts are in registers here)
__global__ __launch_bounds__(256) void k_scan_c(
    const int* __restrict__ cnt, const int* __restrict__ bsum,
    int* __restrict__ S, float* __restrict__ dinv, int n) {
  int t = threadIdx.x;
  int base = blockIdx.x * 1024 + t * 4;
  int v[4];
  if (base + 3 < n) {
    int4 q = *(const int4*)(cnt + base);
    v[0] = q.x; v[1] = q.y; v[2] = q.z; v[3] = q.w;
  } else {
    #pragma unroll
    for (int j = 0; j < 4; ++j) v[j] = (base + j < n) ? cnt[base + j] : 0;
  }
  int tsum = v[0] + v[1] + v[2] + v[3];
  int lane = t & 63, wv = t >> 6;
  int x = tsum;
  #pragma unroll
  for (int off = 1; off < 64; off <<= 1) {
    int u = __shfl_up(x, off);
    if (lane >= off) x += u;
  }
  __shared__ int ws[4];
  if (lane == 63) ws[wv] = x;
  __syncthreads();
  int woff = 0;
  #pragma unroll
  for (int j = 0; j < 4; ++j) if (j < wv) woff += ws[j];
  int run = x - tsum + woff + bsum[blockIdx.x];
  #pragma unroll
  for (int j = 0; j < 4; ++j) {
    int idx = base + j;
    if (idx < n) {
      S[idx] = run;
      dinv[idx] = rsqrtf((float)(v[j] + 1));
      run += v[j];
    }
  }
}

// atomic-free fill: position = S[dst] + rank[e]; store src only.
__global__ void k_fill(const int* __restrict__ ei32, const long long* __restrict__ ei64,
                       int E, int N, const int* __restrict__ S,
                       const int* __restrict__ rank, int* __restrict__ csr,
                       const int* __restrict__ flag) {
  int e = blockIdx.x * blockDim.x + threadIdx.x;
  if (e >= E) return;
  int r = rank[e];
  if (r < 0) return;
  int src, dst;
  if (flag[0]) { src = (int)ei64[e]; dst = (int)ei64[(size_t)E + e]; }
  else         { src = ei32[e];      dst = ei32[(size_t)E + e]; }
  if ((unsigned)src >= (unsigned)N) return;
  csr[S[dst] + r] = src;
}

// fused init: p0 = dinv*x (bf16x2) and hidden32 = temp[0]*x
__global__ void k_init(const float* __restrict__ x, const float* __restrict__ temp,
                       const float* __restrict__ dinv,
                       unsigned* __restrict__ h2, float* __restrict__ hidden,
                       int total64) {
  int i = blockIdx.x * blockDim.x + threadIdx.x;
  if (i >= total64) return;
  float2 xv = ((const float2*)x)[i];
  float di = dinv[i >> 6];                   // wave-uniform-ish broadcast
  h2[i] = bpack(di * xv.x, di * xv.y);
  float t0 = temp[0];
  ((float2*)hidden)[i] = make_float2(t0 * xv.x, t0 * xv.y);
}

// One wave per node. lane = e*16+g: 4 edges per dwordx4 gather instruction,
// 16 edges in flight. Buffers hold p = dinv*h, so gather weight is 1 (tail
// mask only); h_new = dinv*(sum + p_self) applied in the e==0 epilogue.
// mode 0: store p_new bf16 + RMW f32 hidden; mode 1: store final bf16 hidden.
__global__ __launch_bounds__(256) void k_prop(
    const unsigned* __restrict__ h2, unsigned* __restrict__ hnew2,
    float* __restrict__ hidden,
    const int* __restrict__ S, const int* __restrict__ csr,
    const float* __restrict__ dinv, const float* __restrict__ temp,
    int k, int N, int mode) {
  int wid = __builtin_amdgcn_readfirstlane(threadIdx.x >> 6);
  int lane = threadIdx.x & 63;
  int node = blockIdx.x * 4 + wid;           // uniform (SGPR) per wave
  if (node >= N) return;
  int g = lane & 15;                         // feature group: feats 8g..8g+7
  int e = lane >> 4;                         // edge subgroup 0..3
  int s = S[node], en = S[node + 1];
  float acc[8] = {0.f, 0.f, 0.f, 0.f, 0.f, 0.f, 0.f, 0.f};
  for (int p = s; p < en; p += 16) {
    uint4 gd[4];
    float wt[4];
    #pragma unroll
    for (int t = 0; t < 4; ++t) {
      int pj = p + t * 4 + e;
      int sidx = csr[pj < en ? pj : s];      // clamped tail: redundant row, w=0
      wt[t] = (pj < en) ? 1.f : 0.f;
      gd[t] = *(const uint4*)(h2 + (size_t)sidx * 64 + g * 4);  // 16B of row
    }
    #pragma unroll
    for (int t = 0; t < 4; ++t) {
      const unsigned* gu = (const unsigned*)&gd[t];
      #pragma unroll
      for (int u = 0; u < 4; ++u) {
        acc[u * 2]     += wt[t] * blo(gu[u]);
        acc[u * 2 + 1] += wt[t] * bhi(gu[u]);
      }
    }
  }
  #pragma unroll
  for (int u = 0; u < 8; ++u) {              // reduce over the 4 edge subgroups
    acc[u] += __shfl_xor(acc[u], 16);
    acc[u] += __shfl_xor(acc[u], 32);
  }
  if (e == 0) {                              // lanes 0-15 own the epilogue
    float di = dinv[node];
    uint4 gs = *(const uint4*)(h2 + (size_t)node * 64 + g * 4);
    const unsigned* su = (const unsigned*)&gs;
    #pragma unroll
    for (int u = 0; u < 4; ++u) {
      acc[u * 2]     += blo(su[u]);          // self term: p[i], weight 1
      acc[u * 2 + 1] += bhi(su[u]);
    }
    float hn[8];
    #pragma unroll
    for (int u = 0; u < 8; ++u) hn[u] = di * acc[u];   // h_new = dinv * sum
    float tk = temp[k + 1];
    float4* hp = (float4*)(hidden + (size_t)node * NFEAT + g * 8);
    float4 h0 = hp[0], h1 = hp[1];
    h0.x += tk * hn[0];  h0.y += tk * hn[1];
    h0.z += tk * hn[2];  h0.w += tk * hn[3];
    h1.x += tk * hn[4];  h1.y += tk * hn[5];
    h1.z += tk * hn[6];  h1.w += tk * hn[7];
    uint4 pk;
    if (mode == 0) {
      pk.x = bpack(di * hn[0], di * hn[1]);  // p_new = dinv * h_new
      pk.y = bpack(di * hn[2], di * hn[3]);
      pk.z = bpack(di * hn[4], di * hn[5]);
      pk.w = bpack(di * hn[6], di * hn[7]);
      *(uint4*)(hnew2 + (size_t)node * 64 + g * 4) = pk;
      hp[0] = h0;  hp[1] = h1;
    } else {
      pk.x = bpack(h0.x, h0.y);  pk.y = bpack(h0.z, h0.w);
      pk.z = bpack(h1.x, h1.y);  pk.w = bpack(h1.z, h1.w);
      *(uint4*)(hnew2 + (size_t)node * 64 + g * 4) = pk;
    }
  }
}

// hidden_bf16 (Mx128) @ W1 (128x256 f32) + b1, relu -> z1 (Mx256 bf16).
__global__ __launch_bounds__(256) void k_gemm1(
    const unsigned short* __restrict__ Ab, const float* __restrict__ W1,
    const float* __restrict__ b1, unsigned short* __restrict__ z1, int M) {
  __shared__ unsigned short As[64][136];    // m-major, k contig, +8 pad
  __shared__ unsigned short Bs[16][128][8]; // [k>>3][n][k&7]: frag = ds_read_b128
  int tid = threadIdx.x;
  int m0 = blockIdx.x * 64;
  int n0 = blockIdx.y * 128;
  for (int idx = tid; idx < 64 * 16; idx += 256) {
    int m = idx >> 4, c = idx & 15;
    int row = m0 + m; if (row >= M) row = M - 1;
    uint4 v = *(const uint4*)(Ab + (size_t)row * NFEAT + c * 8);
    *(uint4*)&As[m][c * 8] = v;
  }
  for (int idx = tid; idx < 128 * 128; idx += 256) {
    int k = idx >> 7, n = idx & 127;
    Bs[k >> 3][n][k & 7] = (unsigned short)f2bf(W1[(size_t)k * HID + n0 + n]);
  }
  __syncthreads();
  int lane = tid & 63;
  int q = lane >> 4, r16 = lane & 15;
  int nw = (tid >> 6) * 32;
  floatx4 acc[4][2] = {};
  #pragma unroll
  for (int step = 0; step < 4; ++step) {
    int k0 = step * 32;
    short8 a[4], b[2];
    #pragma unroll
    for (int i = 0; i < 4; ++i)
      a[i] = *(const short8*)&As[i * 16 + r16][k0 + q * 8];
    #pragma unroll
    for (int j = 0; j < 2; ++j)
      b[j] = *(const short8*)&Bs[step * 4 + q][nw + j * 16 + r16][0];
    #pragma unroll
    for (int i = 0; i < 4; ++i)
      #pragma unroll
      for (int j = 0; j < 2; ++j)
        acc[i][j] = __builtin_amdgcn_mfma_f32_16x16x32_bf16(a[i], b[j], acc[i][j], 0, 0, 0);
  }
  __syncthreads();
  unsigned short* Zs = &As[0][0];
  #pragma unroll
  for (int j = 0; j < 2; ++j) {
    int n = nw + j * 16 + r16;
    float bias = b1[n0 + n];
    #pragma unroll
    for (int i = 0; i < 4; ++i) {
      #pragma unroll
      for (int r = 0; r < 4; ++r) {
        int m = i * 16 + q * 4 + r;
        float v = fmaxf(acc[i][j][r] + bias, 0.f);
        Zs[m * 136 + n] = (unsigned short)f2bf(v);
      }
    }
  }
  __syncthreads();
  for (int idx = tid; idx < 64 * 16; idx += 256) {
    int m = idx >> 4, c = idx & 15;
    int row = m0 + m;
    if (row < M) {
      uint4 v = *(const uint4*)&Zs[m * 136 + c * 8];
      *(uint4*)(z1 + (size_t)row * HID + n0 + c * 8) = v;
    }
  }
}

// W2 (256x40 f32) -> W2t bf16 [48][256] (n-major, k-contig; n>=40 zero-padded)
__global__ void k_w2prep(const float* __restrict__ W2, unsigned short* __restrict__ W2t) {
  int i = blockIdx.x * blockDim.x + threadIdx.x;
  if (i >= 48 * 256) return;
  int n = i >> 8, k = i & 255;
  W2t[n * 256 + k] = (n < NCLS) ? (unsigned short)f2bf(W2[(size_t)k * NCLS + n]) : 0;
}

// z1 (Mx256 bf16) @ W2t + b2 -> log_softmax -> out f32. LDS-free MFMA.
__global__ __launch_bounds__(256) void k_mlp2(
    const unsigned short* __restrict__ z1, const unsigned short* __restrict__ W2t,
    const float* __restrict__ b2, float* __restrict__ out, int N) {
  int tid = threadIdx.x;
  int lane = tid & 63;
  int wv = tid >> 6;
  int node0 = blockIdx.x * 64 + wv * 16;
  int q = lane >> 4, m = lane & 15;
  int arow = node0 + m; if (arow >= N) arow = N - 1;
  const unsigned short* aptr = z1 + (size_t)arow * HID + q * 8;
  const unsigned short* bptr = W2t + (size_t)m * HID + q * 8;   // + j*16*HID
  floatx4 acc[3] = {};
  #pragma unroll
  for (int step = 0; step < 8; ++step) {     // K = 8 x 32
    short8 a = *(const short8*)(aptr + step * 32);
    #pragma unroll
    for (int j = 0; j < 3; ++j) {
      short8 b = *(const short8*)(bptr + (size_t)j * 16 * HID + step * 32);
      acc[j] = __builtin_amdgcn_mfma_f32_16x16x32_bf16(a, b, acc[j], 0, 0, 0);
    }
  }
  int c = m;                                  // class within tile = col = lane&15
  bool v2 = (c < NCLS - 32);                  // c+32 < 40
  float bb0 = b2[c], bb1 = b2[c + 16];
  float bb2 = v2 ? b2[c + 32] : 0.f;
  #pragma unroll
  for (int r = 0; r < 4; ++r) {
    int node = node0 + q * 4 + r;
    float l0 = acc[0][r] + bb0;
    float l1 = acc[1][r] + bb1;
    float l2 = v2 ? (acc[2][r] + bb2) : -3.4e38f;
    float mx = fmaxf(fmaxf(l0, l1), l2);
    #pragma unroll
    for (int off = 1; off < 16; off <<= 1) mx = fmaxf(mx, __shfl_xor(mx, off));
    float sm = __expf(l0 - mx) + __expf(l1 - mx) + (v2 ? __expf(l2 - mx) : 0.f);
    #pragma unroll
    for (int off = 1; off < 16; off <<= 1) sm += __shfl_xor(sm, off);
    float lse = mx + __logf(sm);
    if (node < N) {
      float* op = out + (size_t)node * NCLS + c;
      op[0] = l0 - lse;
      op[16] = l1 - lse;
      if (v2) op[32] = l2 - lse;
    }
  }
}

extern "C" void kernel_launch(void* const* d_in, const int* in_sizes, int n_in,
                              void* d_out, int out_size, void* d_ws, size_t ws_size,
                              hipStream_t stream) {
  const float*     x    = (const float*)d_in[0];
  const int*       ei32 = (const int*)d_in[1];
  const long long* ei64 = (const long long*)d_in[1];
  const float*     temp = (const float*)d_in[2];
  const float*     W1   = (const float*)d_in[3];
  const float*     b1   = (const float*)d_in[4];
  const float*     W2   = (const float*)d_in[5];
  const float*     b2   = (const float*)d_in[6];
  float* out = (float*)d_out;

  int N = in_sizes[0] / NFEAT;   // 50000
  int E = in_sizes[1] / 2;       // 800000

  // workspace carve (~70 MB)
  char* w = (char*)d_ws;
  auto carve = [&](size_t bytes) -> void* {
    void* p = (void*)w;
    w += (bytes + 255) & ~(size_t)255;
    return p;
  };
  int*      flag      = (int*)     carve(4);
  int*      cnt       = (int*)     carve((size_t)N * 4);
  int*      S         = (int*)     carve(((size_t)N + 1) * 4);
  float*    dinv      = (float*)   carve((size_t)N * 4);
  int*      bsum      = (int*)     carve(1024 * 4);
  unsigned short* W2t = (unsigned short*)carve(48 * 256 * 2);
  int*      rank      = (int*)     carve((size_t)E * 4);
  int*      csr       = (int*)     carve((size_t)E * 4);
  unsigned* h_a       = (unsigned*)carve((size_t)N * 64 * 4);   // bf16x2 p rows
  unsigned* h_b       = (unsigned*)carve((size_t)N * 64 * 4);
  unsigned* hid       = (unsigned*)carve((size_t)N * 64 * 4);   // final hidden bf16
  float*    hidden32  = (float*)   carve((size_t)N * NFEAT * 4);
  unsigned short* z1  = (unsigned short*)hidden32;  // dead before gemm1 writes z1

  int ntiles = (N + 1023) / 1024;   // 49

  k_detect64<<<1, 256, 0, stream>>>((const unsigned int*)d_in[1], flag);
  k_zero<<<(N + 255) / 256, 256, 0, stream>>>(cnt, N);
  k_count<<<(E + 255) / 256, 256, 0, stream>>>(ei32, ei64, E, N, cnt, rank, flag);
  k_scan_a<<<ntiles, 256, 0, stream>>>(cnt, bsum, N);
  k_scan_mid<<<1, 1024, 0, stream>>>(bsum, S, ntiles, N);
  k_scan_c<<<ntiles, 256, 0, stream>>>(cnt, bsum, S, dinv, N);
  k_fill<<<(E + 255) / 256, 256, 0, stream>>>(ei32, ei64, E, N, S, rank, csr, flag);
  k_init<<<(N * 64 + 255) / 256, 256, 0, stream>>>(x, temp, dinv, h_a, hidden32, N * 64);
  k_w2prep<<<48, 256, 0, stream>>>(W2, W2t);

  unsigned* hc = h_a;
  unsigned* hn = h_b;
  for (int k = 0; k < KHOPS - 1; ++k) {
    k_prop<<<(N + 3) / 4, 256, 0, stream>>>(
        hc, hn, hidden32, S, csr, dinv, temp, k, N, 0);
    unsigned* t2 = hc; hc = hn; hn = t2;
  }
  k_prop<<<(N + 3) / 4, 256, 0, stream>>>(
      hc, hid, hidden32, S, csr, dinv, temp, KHOPS - 1, N, 1);

  k_gemm1<<<dim3((N + 63) / 64, 2), 256, 0, stream>>>(
      (const unsigned short*)hid, W1, b1, z1, N);
  k_mlp2<<<(N + 63) / 64, 256, 0, stream>>>(z1, W2t, b2, out, N);
}